// Round 6
// baseline (214.178 us; speedup 1.0000x reference)
//
#include <hip/hip_runtime.h>
#include <hip/hip_bf16.h>

#define NB 128        // batch B
#define NMEM 100000   // N
#define ND 128        // D
constexpr float T_INV = 1.0f / 0.07f;

constexpr int LROW = ND + 8;          // xs LDS row: 136 bf16 = 272 B
constexpr int ZSTRIDE = 16;           // zbuf slots 64 B apart

constexpr int NTW = NMEM / 16;        // 6250 16-n tiles (Z kernel)
constexpr int GRID_Z = 512;           // 2 blocks/CU
constexpr int NWAVES_Z = GRID_Z * 4;  // 2048

constexpr int NFULL = NMEM / 64;      // 1562 full 64-n wave tiles (out kernel)
constexpr int GRID_O = 391;           // 1564 waves: 1562 full + 1 rem(32n) + 1 idle

typedef __attribute__((ext_vector_type(8))) __bf16 bf16x8;
typedef __attribute__((ext_vector_type(4))) float f32x4;
struct bf4 { __bf16 a, b, c, d; };

// A-frag: A[m=lane&15][k=(lane>>4)*8+j]; B-frag: B[n=lane&15][k=(lane>>4)*8+j]
// C/D: col(n)=lane&15, row(m)=(lane>>4)*4+reg   [HW-verified m89/m91]

// ---------------- kernel 1: Z partials + contiguous label peel ----------------
__global__ __launch_bounds__(256, 2) void nce_z(
    const float* __restrict__ x,
    const float* __restrict__ mem_da,
    float* __restrict__ zbuf,
    float* __restrict__ wslbl)
{
  __shared__ __bf16 xs[NB * LROW];
  __shared__ float zl[NB];

  const int tid = threadIdx.x;
  const float4* x4 = (const float4*)x;
  float4 xv[16];
  #pragma unroll
  for (int i = 0; i < 16; ++i) xv[i] = x4[tid + i * 256];
  #pragma unroll
  for (int i = 0; i < 16; ++i) {
    int g4 = tid + i * 256;
    *(bf4*)&xs[(g4 >> 5) * LROW + (g4 & 31) * 4] =
        bf4{(__bf16)xv[i].x, (__bf16)xv[i].y, (__bf16)xv[i].z, (__bf16)xv[i].w};
  }
  if (tid < NB) zl[tid] = 0.f;
  __syncthreads();

  const int wid = tid >> 6, lane = tid & 63, q = lane >> 4, l16 = lane & 15;
  const int wgid = blockIdx.x * 4 + wid;

  f32x4 zacc[8];
  #pragma unroll
  for (int mt = 0; mt < 8; ++mt) zacc[mt] = (f32x4){0.f, 0.f, 0.f, 0.f};

  for (int t = wgid; t < NTW; t += NWAVES_Z) {
    const float* rowp = mem_da + (size_t)(t * 16 + l16) * 129;
    float ln = rowp[0];
    if (q == 0) wslbl[t * 16 + l16] = ln;   // contiguous 64B per tile
    float bfv[4][8];
    #pragma unroll
    for (int kc = 0; kc < 4; ++kc)
      __builtin_memcpy(&bfv[kc][0], rowp + 1 + kc * 32 + q * 8, 32);
    bf16x8 bb[4];
    #pragma unroll
    for (int kc = 0; kc < 4; ++kc)
      #pragma unroll
      for (int j = 0; j < 8; ++j) bb[kc][j] = (__bf16)bfv[kc][j];

    f32x4 acc[8];
    #pragma unroll
    for (int mt = 0; mt < 8; ++mt) acc[mt] = (f32x4){0.f, 0.f, 0.f, 0.f};
    #pragma unroll
    for (int kc = 0; kc < 4; ++kc) {
      const int ko = kc * 32 + q * 8;
      #pragma unroll
      for (int mt = 0; mt < 8; ++mt) {
        bf16x8 a = *(const bf16x8*)&xs[(mt * 16 + l16) * LROW + ko];
        acc[mt] = __builtin_amdgcn_mfma_f32_16x16x32_bf16(a, bb[kc], acc[mt], 0, 0, 0);
      }
    }
    #pragma unroll
    for (int mt = 0; mt < 8; ++mt)
      #pragma unroll
      for (int r = 0; r < 4; ++r)
        zacc[mt][r] += __expf(acc[mt][r] * T_INV);
  }

  #pragma unroll
  for (int mt = 0; mt < 8; ++mt) {
    #pragma unroll
    for (int r = 0; r < 4; ++r) {
      float v = zacc[mt][r];
      v += __shfl_xor(v, 1);
      v += __shfl_xor(v, 2);
      v += __shfl_xor(v, 4);
      v += __shfl_xor(v, 8);
      if (l16 == 0) atomicAdd(&zl[mt * 16 + q * 4 + r], v);
    }
  }
  __syncthreads();
  if (tid < NB) atomicAdd(&zbuf[tid * ZSTRIDE], zl[tid]);
}

// ---------------- kernel 2: mask as streaming outer-product compare ----------------
__global__ __launch_bounds__(256) void nce_mask(
    const int* __restrict__ labels,
    const float* __restrict__ wslbl,
    float* __restrict__ maskout)
{
  const int m = blockIdx.x >> 1;
  const int n0 = (blockIdx.x & 1) * (NMEM / 2);
  const float lbl = (float)labels[m];
  const float4* l4 = (const float4*)(wslbl + n0);
  float4* o4 = (float4*)(maskout + (size_t)m * NMEM + n0);
  for (int i = threadIdx.x; i < (NMEM / 2) / 4; i += 256) {
    float4 v = l4[i];
    o4[i] = make_float4(v.x == lbl ? 1.f : 0.f, v.y == lbl ? 1.f : 0.f,
                        v.z == lbl ? 1.f : 0.f, v.w == lbl ? 1.f : 0.f);
  }
}

// ---------------- kernel 3: normalized out, 64-wide n tiles (256B runs/m-row) ----------------
__global__ __launch_bounds__(256, 2) void nce_out(
    const float* __restrict__ x,
    const float* __restrict__ mem_da,
    const float* __restrict__ zbuf,
    float* __restrict__ out)
{
  __shared__ __bf16 xs[NB * LROW];
  __shared__ float aux[NB];

  const int tid = threadIdx.x;
  const float4* x4 = (const float4*)x;
  float4 xv[16];
  #pragma unroll
  for (int i = 0; i < 16; ++i) xv[i] = x4[tid + i * 256];
  #pragma unroll
  for (int i = 0; i < 16; ++i) {
    int g4 = tid + i * 256;
    *(bf4*)&xs[(g4 >> 5) * LROW + (g4 & 31) * 4] =
        bf4{(__bf16)xv[i].x, (__bf16)xv[i].y, (__bf16)xv[i].z, (__bf16)xv[i].w};
  }
  if (tid < NB) aux[tid] = 1.0f / zbuf[tid * ZSTRIDE];
  __syncthreads();

  const int wid = tid >> 6, lane = tid & 63, q = lane >> 4, l16 = lane & 15;
  const int w = blockIdx.x * 4 + wid;
  const int n0 = w * 64;
  const int nsub = (w < NFULL) ? 4 : ((w == NFULL) ? 2 : 0);
  if (nsub == 0) return;

  f32x4 acc[4][8];
  #pragma unroll
  for (int s = 0; s < 4; ++s)
    #pragma unroll
    for (int mt = 0; mt < 8; ++mt) acc[s][mt] = (f32x4){0.f, 0.f, 0.f, 0.f};

  #pragma unroll
  for (int s = 0; s < 4; ++s) {
    if (s < nsub) {
      const float* rowp = mem_da + (size_t)(n0 + s * 16 + l16) * 129;
      float bfv[4][8];
      #pragma unroll
      for (int kc = 0; kc < 4; ++kc)
        __builtin_memcpy(&bfv[kc][0], rowp + 1 + kc * 32 + q * 8, 32);
      bf16x8 bb[4];
      #pragma unroll
      for (int kc = 0; kc < 4; ++kc)
        #pragma unroll
        for (int j = 0; j < 8; ++j) bb[kc][j] = (__bf16)bfv[kc][j];
      #pragma unroll
      for (int kc = 0; kc < 4; ++kc) {
        const int ko = kc * 32 + q * 8;
        #pragma unroll
        for (int mt = 0; mt < 8; ++mt) {
          bf16x8 a = *(const bf16x8*)&xs[(mt * 16 + l16) * LROW + ko];
          acc[s][mt] = __builtin_amdgcn_mfma_f32_16x16x32_bf16(a, bb[kc], acc[s][mt], 0, 0, 0);
        }
      }
    }
  }

  // epilogue: inner loop over sub-tiles -> 4 consecutive 64B stores per m-row
  #pragma unroll
  for (int mt = 0; mt < 8; ++mt) {
    #pragma unroll
    for (int r = 0; r < 4; ++r) {
      const int m = mt * 16 + q * 4 + r;
      const float rzm = aux[m];
      const size_t base = (size_t)m * NMEM + n0 + l16;
      #pragma unroll
      for (int s = 0; s < 4; ++s)
        if (s < nsub)
          out[base + s * 16] = __expf(acc[s][mt][r] * T_INV) * rzm;
    }
  }
}

extern "C" void kernel_launch(void* const* d_in, const int* in_sizes, int n_in,
                              void* d_out, int out_size, void* d_ws, size_t ws_size,
                              hipStream_t stream) {
  const float* x      = (const float*)d_in[0];
  const int* labels   = (const int*)d_in[2];
  const float* mem_da = (const float*)d_in[3];
  float* out     = (float*)d_out;
  float* maskout = out + (size_t)NB * NMEM;
  float* zbuf    = (float*)d_ws;                      // 8 KB
  float* wslbl   = (float*)((char*)d_ws + 8192);      // 400 KB contiguous labels

  hipMemsetAsync(zbuf, 0, NB * ZSTRIDE * sizeof(float), stream);
  nce_z   <<<GRID_Z, 256, 0, stream>>>(x, mem_da, zbuf, wslbl);
  nce_mask<<<256,    256, 0, stream>>>(labels, wslbl, maskout);
  nce_out <<<GRID_O, 256, 0, stream>>>(x, mem_da, zbuf, out);
}